// Round 13
// baseline (160.876 us; speedup 1.0000x reference)
//
#include <hip/hip_runtime.h>
#include <hip/hip_bf16.h>

#define D 64
#define CAP 32      // slots per node = one 64B line (row == line)
#define OVF_CAP 16384
#define NSHARD 8    // dst shards, bound to XCDs via blockIdx&7 heuristic

__device__ __forceinline__ float bf2f(unsigned short u) {
    return __uint_as_float((unsigned int)u << 16);
}
__device__ __forceinline__ unsigned short f2bf(float f) {
    unsigned int u = __float_as_uint(f);
    unsigned int r = (u + 0x7fffu + ((u >> 16) & 1u)) >> 16;   // RNE
    return (unsigned short)r;
}

// ---------- Kernel 1: m planes = bf16(relu(x @ W + b)); zero cnt + ovf_cnt ----------
__global__ __launch_bounds__(256) void node_mlp_kernel(
    const float* __restrict__ x, const float* __restrict__ W,
    const float* __restrict__ b, unsigned short* __restrict__ m0,
    unsigned short* __restrict__ m1, int* __restrict__ cnt,
    int* __restrict__ ovf_cnt, int n_nodes) {
    for (int i = blockIdx.x * blockDim.x + threadIdx.x; i < n_nodes;
         i += gridDim.x * blockDim.x) cnt[i] = 0;
    if (blockIdx.x == 0 && threadIdx.x == 0) *ovf_cnt = 0;

    const int lane = threadIdx.x & 63;
    const int l31 = lane & 31;
    unsigned short* mp = (lane < 32) ? m0 : m1;
    float w[D];
    #pragma unroll
    for (int k = 0; k < D; ++k) w[k] = W[k * D + lane];
    const float bias = b[lane];

    const int wave = (blockIdx.x * blockDim.x + threadIdx.x) >> 6;
    const int nwaves = (gridDim.x * blockDim.x) >> 6;

    for (int row = wave; row < n_nodes; row += nwaves) {
        const float4* xr = (const float4*)(x + (size_t)row * D);
        float acc = bias;
        #pragma unroll
        for (int kk = 0; kk < D / 4; ++kk) {
            float4 xv = xr[kk];   // wave-uniform address -> broadcast, 1 request
            acc = fmaf(xv.x, w[4 * kk + 0], acc);
            acc = fmaf(xv.y, w[4 * kk + 1], acc);
            acc = fmaf(xv.z, w[4 * kk + 2], acc);
            acc = fmaf(xv.w, w[4 * kk + 3], acc);
        }
        mp[(size_t)row * 32 + l31] = f2bf(fmaxf(acc, 0.0f));
    }
}

// ---------- Kernel 2: XCD-sharded append (round 12 win — unchanged) ----------
__global__ __launch_bounds__(256) void append_kernel(
    const int* __restrict__ src, const int* __restrict__ dst,
    int* __restrict__ cnt, unsigned short* __restrict__ slots,
    int* __restrict__ ovf_cnt, unsigned int* __restrict__ ovf,
    int n_edges, int blocks_per_shard) {
    const int shard = blockIdx.x & (NSHARD - 1);
    const int p = blockIdx.x >> 3;          // rank within shard group
    const int chunk = (n_edges + blocks_per_shard - 1) / blocks_per_shard;
    const int beg = p * chunk;
    const int end = min(beg + chunk, n_edges);

    for (int e = beg + (int)threadIdx.x; e < end; e += 256) {
        int d = dst[e];                      // coalesced; L3-served (8x redundant)
        if ((d & (NSHARD - 1)) != shard) continue;
        int s = src[e];
        int pos = atomicAdd(&cnt[d], 1);     // memory-side atomic
        if (pos < CAP) {
            slots[(size_t)d * CAP + pos] = (unsigned short)s;
        } else {                             // ~4 nodes expected (P(deg>32)~8e-5)
            int op = atomicAdd(ovf_cnt, 1);
            if (op < OVF_CAP)
                ovf[op] = ((unsigned int)d << 16) | (unsigned int)s;
        }
    }
}

// ---------- Kernel 3: gather — one wave per node, scalar slot row, no shfl ----------
// lanes 0..31 -> plane0 (cols 0..31), lanes 32..63 -> plane1 (cols 32..63);
// out column == lane. node is wave-uniform (readfirstlane) so cnt and the
// 64B slot row are scalar (s_load) and loop bounds are divergence-free.
__global__ __launch_bounds__(256) void gather_kernel(
    const unsigned short* __restrict__ slots, const int* __restrict__ cnt,
    const unsigned short* __restrict__ m0, const unsigned short* __restrict__ m1,
    const int* __restrict__ ovf_cnt, const unsigned int* __restrict__ ovf,
    float* __restrict__ out, int n_nodes) {
    int node = blockIdx.x * 4 + (threadIdx.x >> 6);
    if (node >= n_nodes) return;           // wave-uniform branch
    node = __builtin_amdgcn_readfirstlane(node);

    const int lane = threadIdx.x & 63;
    const int l31 = lane & 31;
    const unsigned short* __restrict__ mplane = (lane < 32) ? m0 : m1;

    const int c = cnt[node];               // scalar load
    const int cc = min(c, CAP);
    const unsigned int* __restrict__ row =
        (const unsigned int*)(slots + (size_t)node * CAP);  // scalar base

    float acc = 0.0f;
    int k = 0;
    for (; k + 8 <= cc; k += 8) {
        unsigned int p0 = row[(k >> 1) + 0];   // s_load: 4 dwords = 8 slots
        unsigned int p1 = row[(k >> 1) + 1];
        unsigned int p2 = row[(k >> 1) + 2];
        unsigned int p3 = row[(k >> 1) + 3];
        unsigned int s0 = p0 & 0xFFFFu, s1 = p0 >> 16;
        unsigned int s2 = p1 & 0xFFFFu, s3 = p1 >> 16;
        unsigned int s4 = p2 & 0xFFFFu, s5 = p2 >> 16;
        unsigned int s6 = p3 & 0xFFFFu, s7 = p3 >> 16;
        float v0 = bf2f(mplane[(size_t)s0 * 32 + l31]);  // 8 loads in flight,
        float v1 = bf2f(mplane[(size_t)s1 * 32 + l31]);  // SGPR base + small voffset
        float v2 = bf2f(mplane[(size_t)s2 * 32 + l31]);
        float v3 = bf2f(mplane[(size_t)s3 * 32 + l31]);
        float v4 = bf2f(mplane[(size_t)s4 * 32 + l31]);
        float v5 = bf2f(mplane[(size_t)s5 * 32 + l31]);
        float v6 = bf2f(mplane[(size_t)s6 * 32 + l31]);
        float v7 = bf2f(mplane[(size_t)s7 * 32 + l31]);
        acc += ((v0 + v1) + (v2 + v3)) + ((v4 + v5) + (v6 + v7));
    }
    for (; k < cc; ++k) {
        unsigned int p = row[k >> 1];
        unsigned int s = (k & 1) ? (p >> 16) : (p & 0xFFFFu);
        acc += bf2f(mplane[(size_t)s * 32 + l31]);
    }
    if (c > CAP) {                          // rare: scan tiny ovf list (uniform)
        int oc = min(*ovf_cnt, OVF_CAP);
        for (int i = 0; i < oc; ++i) {
            unsigned int e = ovf[i];
            if ((int)(e >> 16) == node)
                acc += bf2f(mplane[(size_t)(e & 0xFFFFu) * 32 + l31]);
        }
    }
    out[(size_t)node * D + lane] = acc;     // fully coalesced 256B/wave
}

// ---------- Fallback: atomic scatter (plane layout) ----------
__global__ __launch_bounds__(256) void edge_scatter_kernel(
    const int* __restrict__ src, const int* __restrict__ dst,
    const unsigned short* __restrict__ m0, const unsigned short* __restrict__ m1,
    float* __restrict__ out, int n_edges) {
    long long t = (long long)blockIdx.x * blockDim.x + threadIdx.x;
    int e = (int)(t >> 4);
    if (e >= n_edges) return;
    int c = (int)(t & 15) << 2;
    int s = src[e];
    int d = dst[e];
    const unsigned short* mp = (c < 32) ? m0 : m1;
    const ushort4 v = *(const ushort4*)(mp + (size_t)s * 32 + (c & 31));
    float* o = out + (size_t)d * D + c;
    atomicAdd(o + 0, bf2f(v.x));
    atomicAdd(o + 1, bf2f(v.y));
    atomicAdd(o + 2, bf2f(v.z));
    atomicAdd(o + 3, bf2f(v.w));
}

static inline size_t align_up(size_t v, size_t a) { return (v + a - 1) & ~(a - 1); }

extern "C" void kernel_launch(void* const* d_in, const int* in_sizes, int n_in,
                              void* d_out, int out_size, void* d_ws, size_t ws_size,
                              hipStream_t stream) {
    const float* x = (const float*)d_in[0];
    const int* edge_index = (const int*)d_in[1];   // int32 per harness contract
    const float* W = (const float*)d_in[2];
    const float* b = (const float*)d_in[3];
    float* out = (float*)d_out;

    const int n_nodes = in_sizes[0] / D;        // 50000
    const int n_edges = in_sizes[1] / 2;        // 800000
    const int* src = edge_index;                // row 0 (j, gather)
    const int* dst = edge_index + n_edges;      // row 1 (i, scatter)

    // Workspace layout (~10 MB total)
    size_t off = 0;
    unsigned short* m0 = (unsigned short*)((char*)d_ws + off);
    off = align_up(off + (size_t)n_nodes * 32 * sizeof(unsigned short), 256);
    unsigned short* m1 = (unsigned short*)((char*)d_ws + off);
    off = align_up(off + (size_t)n_nodes * 32 * sizeof(unsigned short), 256);
    int* cnt = (int*)((char*)d_ws + off);
    off = align_up(off + (size_t)n_nodes * sizeof(int), 256);
    unsigned short* slots = (unsigned short*)((char*)d_ws + off);
    off = align_up(off + (size_t)n_nodes * CAP * sizeof(unsigned short), 256);
    int* ovf_cnt = (int*)((char*)d_ws + off);
    off = align_up(off + sizeof(int), 256);
    unsigned int* ovf = (unsigned int*)((char*)d_ws + off);
    off = align_up(off + (size_t)OVF_CAP * sizeof(unsigned int), 256);
    const size_t needed = off;

    // Node MLP (+ fused cnt/ovf zeroing): 512 blocks -> 8 waves/CU
    node_mlp_kernel<<<512, 256, 0, stream>>>(x, W, b, m0, m1, cnt, ovf_cnt, n_nodes);

    if (ws_size >= needed && n_nodes <= 65536) {
        const int blocks_per_shard = 128;           // 1024 blocks total
        append_kernel<<<blocks_per_shard * NSHARD, 256, 0, stream>>>(
            src, dst, cnt, slots, ovf_cnt, ovf, n_edges, blocks_per_shard);
        gather_kernel<<<(n_nodes + 3) / 4, 256, 0, stream>>>(
            slots, cnt, m0, m1, ovf_cnt, ovf, out, n_nodes);
    } else {
        hipMemsetAsync(d_out, 0, (size_t)out_size * sizeof(float), stream);
        long long total_threads = (long long)n_edges * 16;
        int scat_blocks = (int)((total_threads + 255) / 256);
        edge_scatter_kernel<<<scat_blocks, 256, 0, stream>>>(src, dst, m0, m1,
                                                             out, n_edges);
    }
}